// Round 1
// baseline (874.547 us; speedup 1.0000x reference)
//
#include <hip/hip_runtime.h>
#include <hip/hip_bf16.h>
#include <cstdint>
#include <cstddef>

// RGCN layer: out = (x@W0 + sum_r h_r@W[r]) / max(deg,1)
//   h_r[dst] = sum over edges (src->dst, type r) of x[src]
// Pipeline: detect idx dtype -> normalize+deg hist -> scan -> CSR scatter ->
//           per-node wave aggregation (h, bf16) -> f32 GEMM [N,1152]@[1152,128] + scale.
// ws usage: ~116 MB (st, darr, deg, row_start, cursor, esorted, h bf16, invdeg).

#define NDIM 128
#define NREL 8

// ---------- K0: zero int buffer ----------
__global__ void k_zero(int* p, int n){
  int i = blockIdx.x * 256 + threadIdx.x;
  if (i < n) p[i] = 0;
}

// ---------- K1: detect int64 vs int32 edge arrays ----------
// int64 values < 2^31 => every odd 32-bit word is 0. For real int32 data the
// odd words are src values (P(all 64 == 0) ~ (1/50000)^64 ~ 0).
__global__ void k_detect(const int* ei, int* flag){
  int v = ei[2 * threadIdx.x + 1];
  unsigned long long b = __ballot(v == 0);
  if (threadIdx.x == 0) flag[0] = (b == ~0ull) ? 1 : 0;
}

// ---------- K2: normalize edges + degree histogram ----------
__global__ void k_norm(const int* ei, const int* et, const int* __restrict__ flag,
                       int* st, int* darr, int* deg, int E){
  int e = blockIdx.x * 256 + threadIdx.x;
  if (e >= E) return;
  int is64 = flag[0];
  int s, d, t;
  if (is64){ s = ei[2*e]; d = ei[2*(E + e)]; t = et[2*e]; }
  else     { s = ei[e];   d = ei[E + e];     t = et[e];   }
  st[e]   = s | (t << 20);      // src < 2^20, type in [0,8)
  darr[e] = d;
  atomicAdd(&deg[d], 1);
}

// ---------- K3/K4/K5: exclusive scan of deg -> row_start, cursor ----------
__global__ void k_scanA(const int* deg, int* rs, int* bsum, int N){
  __shared__ int sm[256];
  int t = threadIdx.x, i = blockIdx.x * 256 + t;
  int v = (i < N) ? deg[i] : 0;
  sm[t] = v; __syncthreads();
  #pragma unroll
  for (int off = 1; off < 256; off <<= 1){
    int xv = 0; if (t >= off) xv = sm[t - off];
    __syncthreads(); sm[t] += xv; __syncthreads();
  }
  if (i < N) rs[i] = sm[t] - v;          // exclusive (partial, per block)
  if (t == 255) bsum[blockIdx.x] = sm[255];
}

__global__ void k_scanB(const int* bsum, int* boff, int nblk){
  __shared__ int sm[256];
  int t = threadIdx.x;
  int v = (t < nblk) ? bsum[t] : 0;
  sm[t] = v; __syncthreads();
  #pragma unroll
  for (int off = 1; off < 256; off <<= 1){
    int xv = 0; if (t >= off) xv = sm[t - off];
    __syncthreads(); sm[t] += xv; __syncthreads();
  }
  boff[t] = sm[t] - v;
}

__global__ void k_scanC(int* rs, int* cursor, const int* boff, int N, int E){
  int i = blockIdx.x * 256 + threadIdx.x;
  if (i < N){
    int v = rs[i] + boff[blockIdx.x];
    rs[i] = v; cursor[i] = v;
  }
  if (i == 0) rs[N] = E;
}

// ---------- K6: scatter edges into CSR buckets ----------
__global__ void k_scatter(const int* st, const int* darr, int* cursor, int* esort, int E){
  int e = blockIdx.x * 256 + threadIdx.x;
  if (e >= E) return;
  int pos = atomicAdd(&cursor[darr[e]], 1);
  esort[pos] = st[e];
}

// ---------- K7: per-node aggregation -> h[r][n][:] (bf16), invdeg ----------
// One wave per dst node. lane owns cols {2*lane, 2*lane+1}. 8 relation
// accumulators = 16 VGPRs. Relation switch is wave-uniform (scalar branch).
__global__ __launch_bounds__(256) void k_agg(const float* __restrict__ x,
                                             const int* __restrict__ rs,
                                             const int* __restrict__ esort,
                                             __hip_bfloat162* __restrict__ h,
                                             float* __restrict__ invdeg, int N){
  int wave = threadIdx.x >> 6;
  int lane = threadIdx.x & 63;
  int n = blockIdx.x * 4 + wave;
  if (n >= N) return;
  int beg = rs[n], end = rs[n + 1];
  float2 acc[NREL];
  #pragma unroll
  for (int r = 0; r < NREL; ++r){ acc[r].x = 0.f; acc[r].y = 0.f; }
  const float2* x2 = (const float2*)x;
  for (int i = beg; i < end; ++i){
    int p   = esort[i];          // same addr across wave -> broadcast
    int src = p & 0xFFFFF;
    int t   = p >> 20;
    float2 xv = x2[(size_t)src * 64 + lane];
    switch (t){                  // wave-uniform
      case 0: acc[0].x += xv.x; acc[0].y += xv.y; break;
      case 1: acc[1].x += xv.x; acc[1].y += xv.y; break;
      case 2: acc[2].x += xv.x; acc[2].y += xv.y; break;
      case 3: acc[3].x += xv.x; acc[3].y += xv.y; break;
      case 4: acc[4].x += xv.x; acc[4].y += xv.y; break;
      case 5: acc[5].x += xv.x; acc[5].y += xv.y; break;
      case 6: acc[6].x += xv.x; acc[6].y += xv.y; break;
      case 7: acc[7].x += xv.x; acc[7].y += xv.y; break;
    }
  }
  size_t base = (size_t)n * 64 + lane;
  #pragma unroll
  for (int r = 0; r < NREL; ++r)
    h[(size_t)r * N * 64 + base] = __float22bfloat162_rn(acc[r]);
  if (lane == 0){
    int d = end - beg;
    invdeg[n] = 1.0f / (float)(d > 0 ? d : 1);
  }
}

// ---------- K8: out[n][j] = (sum_{r,k} h/x * W) * invdeg[n] ----------
// 32 rows/block, 128 threads, thread owns 8 rows x 4 cols (32 f32 acc).
// W[r] staged in LDS f32 (64KB) + A tile (16KB) -> 80KB, 2 blocks/CU.
__global__ __launch_bounds__(128) void k_gemm(const float* __restrict__ x,
                                              const __hip_bfloat16* __restrict__ h,
                                              const float* __restrict__ W,
                                              const float* __restrict__ W0,
                                              const float* __restrict__ invdeg,
                                              float* __restrict__ out, int N){
  __shared__ float As[32][NDIM];
  __shared__ float Ws[NDIM][NDIM];
  int n0 = blockIdx.x * 32;
  int j4 = (threadIdx.x & 31) * 4;   // 4 consecutive cols
  int q  = threadIdx.x >> 5;         // 0..3 -> rows q*8..q*8+7
  float acc[8][4];
  #pragma unroll
  for (int m = 0; m < 8; ++m)
    #pragma unroll
    for (int c = 0; c < 4; ++c) acc[m][c] = 0.f;

  for (int r = 0; r < NREL + 1; ++r){
    const float* Wsrc = (r < NREL) ? (W + (size_t)r * NDIM * NDIM) : W0;
    for (int idx = threadIdx.x; idx < NDIM * NDIM; idx += 128)
      Ws[idx >> 7][idx & 127] = Wsrc[idx];
    for (int idx = threadIdx.x; idx < 32 * NDIM; idx += 128){
      int row = idx >> 7, k = idx & 127, n = n0 + row;
      float v = 0.f;
      if (n < N)
        v = (r < NREL) ? __bfloat162float(h[((size_t)r * N + n) * NDIM + k])
                       : x[(size_t)n * NDIM + k];
      As[row][k] = v;
    }
    __syncthreads();
    #pragma unroll 4
    for (int k4 = 0; k4 < 32; ++k4){
      const float4 w0 = *(const float4*)&Ws[k4*4 + 0][j4];
      const float4 w1 = *(const float4*)&Ws[k4*4 + 1][j4];
      const float4 w2 = *(const float4*)&Ws[k4*4 + 2][j4];
      const float4 w3 = *(const float4*)&Ws[k4*4 + 3][j4];
      #pragma unroll
      for (int m = 0; m < 8; ++m){
        const float4 a = *(const float4*)&As[q*8 + m][k4*4];
        acc[m][0] = fmaf(a.x, w0.x, fmaf(a.y, w1.x, fmaf(a.z, w2.x, fmaf(a.w, w3.x, acc[m][0]))));
        acc[m][1] = fmaf(a.x, w0.y, fmaf(a.y, w1.y, fmaf(a.z, w2.y, fmaf(a.w, w3.y, acc[m][1]))));
        acc[m][2] = fmaf(a.x, w0.z, fmaf(a.y, w1.z, fmaf(a.z, w2.z, fmaf(a.w, w3.z, acc[m][2]))));
        acc[m][3] = fmaf(a.x, w0.w, fmaf(a.y, w1.w, fmaf(a.z, w2.w, fmaf(a.w, w3.w, acc[m][3]))));
      }
    }
    __syncthreads();
  }
  #pragma unroll
  for (int m = 0; m < 8; ++m){
    int n = n0 + q*8 + m;
    if (n < N){
      float inv = invdeg[n];
      float4 o = make_float4(acc[m][0]*inv, acc[m][1]*inv, acc[m][2]*inv, acc[m][3]*inv);
      *(float4*)&out[(size_t)n * NDIM + j4] = o;
    }
  }
}

extern "C" void kernel_launch(void* const* d_in, const int* in_sizes, int n_in,
                              void* d_out, int out_size, void* d_ws, size_t ws_size,
                              hipStream_t stream){
  const float* x  = (const float*)d_in[0];
  const int*   ei = (const int*)d_in[1];
  const int*   et = (const int*)d_in[2];
  const float* W  = (const float*)d_in[4];
  const float* W0 = (const float*)d_in[5];
  float* out = (float*)d_out;

  const int N = in_sizes[0] / NDIM;   // 50000
  const int E = in_sizes[2];          // 800000

  char* ws = (char*)d_ws;
  size_t off = 0;
  auto alloc = [&](size_t bytes)->size_t{
    size_t p = off; off = (off + bytes + 255) & ~(size_t)255; return p;
  };
  size_t o_flag = alloc(4);
  size_t o_st   = alloc((size_t)E * 4);
  size_t o_d    = alloc((size_t)E * 4);
  size_t o_deg  = alloc((size_t)N * 4);
  size_t o_rs   = alloc((size_t)(N + 1) * 4);
  size_t o_cur  = alloc((size_t)N * 4);
  size_t o_bs   = alloc(256 * 4);
  size_t o_bo   = alloc(256 * 4);
  size_t o_es   = alloc((size_t)E * 4);
  size_t o_h    = alloc((size_t)NREL * N * NDIM * 2);   // bf16
  size_t o_inv  = alloc((size_t)N * 4);
  (void)ws_size; (void)o_inv; // ~116 MB total

  int*  flag   = (int*)(ws + o_flag);
  int*  st     = (int*)(ws + o_st);
  int*  darr   = (int*)(ws + o_d);
  int*  deg    = (int*)(ws + o_deg);
  int*  rs     = (int*)(ws + o_rs);
  int*  cursor = (int*)(ws + o_cur);
  int*  bsum   = (int*)(ws + o_bs);
  int*  boff   = (int*)(ws + o_bo);
  int*  esort  = (int*)(ws + o_es);
  __hip_bfloat162* h2 = (__hip_bfloat162*)(ws + o_h);
  __hip_bfloat16*  h1 = (__hip_bfloat16*)(ws + o_h);
  float* invdeg = (float*)(ws + o_inv);

  const int nblk = (N + 255) / 256;       // 196
  const int eblk = (E + 255) / 256;       // 3125

  k_zero<<<nblk, 256, 0, stream>>>(deg, N);
  k_detect<<<1, 64, 0, stream>>>(ei, flag);
  k_norm<<<eblk, 256, 0, stream>>>(ei, et, flag, st, darr, deg, E);
  k_scanA<<<nblk, 256, 0, stream>>>(deg, rs, bsum, N);
  k_scanB<<<1, 256, 0, stream>>>(bsum, boff, nblk);
  k_scanC<<<nblk, 256, 0, stream>>>(rs, cursor, boff, N, E);
  k_scatter<<<eblk, 256, 0, stream>>>(st, darr, cursor, esort, E);
  k_agg<<<(N + 3) / 4, 256, 0, stream>>>(x, rs, esort, h2, invdeg, N);
  k_gemm<<<(N + 31) / 32, 128, 0, stream>>>(x, h1, W, W0, invdeg, out, N);
}

// Round 2
// 297.536 us; speedup vs baseline: 2.9393x; 2.9393x over previous
//
#include <hip/hip_runtime.h>
#include <hip/hip_bf16.h>
#include <cstdint>
#include <cstddef>

// RGCN layer: out = (x@W0 + sum_r h_r@W[r]) / max(deg,1)
//   h_r[dst] = sum over edges (src->dst, type r) of x[src]
// Pipeline: detect idx dtype -> normalize+deg hist -> scan -> CSR scatter ->
//           per-node wave aggregation (h, bf16) -> bf16 MFMA GEMM (no LDS) + scale.

#define NDIM 128
#define NREL 8

typedef __attribute__((ext_vector_type(8))) short bf16x8;   // 8 bf16 = 4 VGPR
typedef __attribute__((ext_vector_type(4))) float f32x4;    // MFMA acc

__device__ __forceinline__ short f2bf(float f){
  __hip_bfloat16 h = __float2bfloat16(f);
  return *reinterpret_cast<short*>(&h);
}

// ---------- K0: zero int buffer ----------
__global__ void k_zero(int* p, int n){
  int i = blockIdx.x * 256 + threadIdx.x;
  if (i < n) p[i] = 0;
}

// ---------- K1: detect int64 vs int32 edge arrays ----------
__global__ void k_detect(const int* ei, int* flag){
  int v = ei[2 * threadIdx.x + 1];
  unsigned long long b = __ballot(v == 0);
  if (threadIdx.x == 0) flag[0] = (b == ~0ull) ? 1 : 0;
}

// ---------- K2: normalize edges + degree histogram ----------
__global__ void k_norm(const int* ei, const int* et, const int* __restrict__ flag,
                       int* st, int* darr, int* deg, int E){
  int e = blockIdx.x * 256 + threadIdx.x;
  if (e >= E) return;
  int is64 = flag[0];
  int s, d, t;
  if (is64){ s = ei[2*e]; d = ei[2*(E + e)]; t = et[2*e]; }
  else     { s = ei[e];   d = ei[E + e];     t = et[e];   }
  st[e]   = s | (t << 20);      // src < 2^20, type in [0,8)
  darr[e] = d;
  atomicAdd(&deg[d], 1);
}

// ---------- K3/K4/K5: exclusive scan of deg -> row_start, cursor ----------
__global__ void k_scanA(const int* deg, int* rs, int* bsum, int N){
  __shared__ int sm[256];
  int t = threadIdx.x, i = blockIdx.x * 256 + t;
  int v = (i < N) ? deg[i] : 0;
  sm[t] = v; __syncthreads();
  #pragma unroll
  for (int off = 1; off < 256; off <<= 1){
    int xv = 0; if (t >= off) xv = sm[t - off];
    __syncthreads(); sm[t] += xv; __syncthreads();
  }
  if (i < N) rs[i] = sm[t] - v;
  if (t == 255) bsum[blockIdx.x] = sm[255];
}

__global__ void k_scanB(const int* bsum, int* boff, int nblk){
  __shared__ int sm[256];
  int t = threadIdx.x;
  int v = (t < nblk) ? bsum[t] : 0;
  sm[t] = v; __syncthreads();
  #pragma unroll
  for (int off = 1; off < 256; off <<= 1){
    int xv = 0; if (t >= off) xv = sm[t - off];
    __syncthreads(); sm[t] += xv; __syncthreads();
  }
  boff[t] = sm[t] - v;
}

__global__ void k_scanC(int* rs, int* cursor, const int* boff, int N, int E){
  int i = blockIdx.x * 256 + threadIdx.x;
  if (i < N){
    int v = rs[i] + boff[blockIdx.x];
    rs[i] = v; cursor[i] = v;
  }
  if (i == 0) rs[N] = E;
}

// ---------- K6: scatter edges into CSR buckets ----------
__global__ void k_scatter(const int* st, const int* darr, int* cursor, int* esort, int E){
  int e = blockIdx.x * 256 + threadIdx.x;
  if (e >= E) return;
  int pos = atomicAdd(&cursor[darr[e]], 1);
  esort[pos] = st[e];
}

// ---------- K7: per-node aggregation -> h[r][n][:] (bf16), invdeg ----------
__global__ __launch_bounds__(256) void k_agg(const float* __restrict__ x,
                                             const int* __restrict__ rs,
                                             const int* __restrict__ esort,
                                             __hip_bfloat162* __restrict__ h,
                                             float* __restrict__ invdeg, int N){
  int wave = threadIdx.x >> 6;
  int lane = threadIdx.x & 63;
  int n = blockIdx.x * 4 + wave;
  if (n >= N) return;
  int beg = rs[n], end = rs[n + 1];
  float2 acc[NREL];
  #pragma unroll
  for (int r = 0; r < NREL; ++r){ acc[r].x = 0.f; acc[r].y = 0.f; }
  const float2* x2 = (const float2*)x;
  for (int i = beg; i < end; ++i){
    int p   = esort[i];          // same addr across wave -> broadcast
    int src = p & 0xFFFFF;
    int t   = p >> 20;
    float2 xv = x2[(size_t)src * 64 + lane];
    switch (t){                  // wave-uniform
      case 0: acc[0].x += xv.x; acc[0].y += xv.y; break;
      case 1: acc[1].x += xv.x; acc[1].y += xv.y; break;
      case 2: acc[2].x += xv.x; acc[2].y += xv.y; break;
      case 3: acc[3].x += xv.x; acc[3].y += xv.y; break;
      case 4: acc[4].x += xv.x; acc[4].y += xv.y; break;
      case 5: acc[5].x += xv.x; acc[5].y += xv.y; break;
      case 6: acc[6].x += xv.x; acc[6].y += xv.y; break;
      case 7: acc[7].x += xv.x; acc[7].y += xv.y; break;
    }
  }
  size_t base = (size_t)n * 64 + lane;
  #pragma unroll
  for (int r = 0; r < NREL; ++r)
    h[(size_t)r * N * 64 + base] = __float22bfloat162_rn(acc[r]);
  if (lane == 0){
    int d = end - beg;
    invdeg[n] = 1.0f / (float)(d > 0 ? d : 1);
  }
}

// ---------- K8a: W,W0 -> Wb[9][j][k] bf16 (transposed: B^T layout) ----------
__global__ void k_wcast(const float* __restrict__ W, const float* __restrict__ W0,
                        short* __restrict__ Wb){
  int i = blockIdx.x * 256 + threadIdx.x;      // 9*128*128 = 147456
  if (i >= 9 * NDIM * NDIM) return;
  int r = i >> 14;
  int j = (i >> 7) & 127;
  int k = i & 127;
  const float* src = (r < NREL) ? (W + ((size_t)r << 14)) : W0;
  Wb[i] = f2bf(src[k * NDIM + j]);             // Wb[r][j][k] = W[r][k][j]
}

// ---------- K8b: MFMA GEMM: out[n][j] = (sum_r h_r@W[r] + x@W0) * invdeg ----------
// BM=64 rows/block, 4 waves, wave tile 32x64 (2x4 fragments of 16x16x32).
// No LDS: A/B fragments loaded directly from global (lane quads form 64B segments).
__global__ __launch_bounds__(256) void k_mfma(
    const __hip_bfloat16* __restrict__ h,   // [8][N][128]
    const float* __restrict__ x,            // [N][128]
    const short* __restrict__ Wb,           // [9][128][128]  (j-major, bf16)
    const float* __restrict__ invdeg,
    float* __restrict__ out, int N)
{
  const int lane = threadIdx.x & 63;
  const int wid  = threadIdx.x >> 6;
  const int wr   = wid >> 1;            // 0..1 : row half
  const int wc   = wid & 1;             // 0..1 : col half
  const int n0   = blockIdx.x * 64;
  const int lr   = lane & 15;
  const int koff = (lane >> 4) * 8;

  f32x4 acc[2][4];
  #pragma unroll
  for (int m = 0; m < 2; ++m)
    #pragma unroll
    for (int p = 0; p < 4; ++p)
      acc[m][p] = (f32x4){0.f, 0.f, 0.f, 0.f};

  int row[2], col[4];
  #pragma unroll
  for (int m = 0; m < 2; ++m){
    int rr = n0 + wr * 32 + m * 16 + lr;
    row[m] = rr < N ? rr : N - 1;       // clamp: stays in-bounds, result discarded
  }
  #pragma unroll
  for (int p = 0; p < 4; ++p) col[p] = wc * 64 + p * 16 + lr;

  // 8 relation terms: A = h_r (bf16)
  for (int r = 0; r < NREL; ++r){
    const __hip_bfloat16* hb = h + (((size_t)r * N) << 7);
    const short* wbase = Wb + ((size_t)r << 14);
    #pragma unroll
    for (int kk = 0; kk < 4; ++kk){
      const int k0 = kk * 32 + koff;
      bf16x8 a[2], b[4];
      #pragma unroll
      for (int m = 0; m < 2; ++m)
        a[m] = *(const bf16x8*)(hb + (((size_t)row[m]) << 7) + k0);
      #pragma unroll
      for (int p = 0; p < 4; ++p)
        b[p] = *(const bf16x8*)(wbase + (((size_t)col[p]) << 7) + k0);
      #pragma unroll
      for (int m = 0; m < 2; ++m)
        #pragma unroll
        for (int p = 0; p < 4; ++p)
          acc[m][p] = __builtin_amdgcn_mfma_f32_16x16x32_bf16(a[m], b[p], acc[m][p], 0, 0, 0);
    }
  }

  // W0 term: A = x (f32 -> bf16 in-register)
  {
    const short* wbase = Wb + ((size_t)NREL << 14);
    #pragma unroll
    for (int kk = 0; kk < 4; ++kk){
      const int k0 = kk * 32 + koff;
      bf16x8 a[2], b[4];
      #pragma unroll
      for (int m = 0; m < 2; ++m){
        const float* xp = x + (((size_t)row[m]) << 7) + k0;
        float4 f0 = *(const float4*)(xp);
        float4 f1 = *(const float4*)(xp + 4);
        bf16x8 t;
        t[0] = f2bf(f0.x); t[1] = f2bf(f0.y); t[2] = f2bf(f0.z); t[3] = f2bf(f0.w);
        t[4] = f2bf(f1.x); t[5] = f2bf(f1.y); t[6] = f2bf(f1.z); t[7] = f2bf(f1.w);
        a[m] = t;
      }
      #pragma unroll
      for (int p = 0; p < 4; ++p)
        b[p] = *(const bf16x8*)(wbase + (((size_t)col[p]) << 7) + k0);
      #pragma unroll
      for (int m = 0; m < 2; ++m)
        #pragma unroll
        for (int p = 0; p < 4; ++p)
          acc[m][p] = __builtin_amdgcn_mfma_f32_16x16x32_bf16(a[m], b[p], acc[m][p], 0, 0, 0);
    }
  }

  // Epilogue: C/D layout col=lane&15, row=(lane>>4)*4+v  [m89/m91 verified]
  #pragma unroll
  for (int m = 0; m < 2; ++m){
    int rbase = n0 + wr * 32 + m * 16 + (lane >> 4) * 4;
    #pragma unroll
    for (int v = 0; v < 4; ++v){
      int ro = rbase + v;
      if (ro < N){
        float inv = invdeg[ro];
        #pragma unroll
        for (int p = 0; p < 4; ++p)
          out[(((size_t)ro) << 7) + wc * 64 + p * 16 + lr] = acc[m][p][v] * inv;
      }
    }
  }
}

extern "C" void kernel_launch(void* const* d_in, const int* in_sizes, int n_in,
                              void* d_out, int out_size, void* d_ws, size_t ws_size,
                              hipStream_t stream){
  const float* x  = (const float*)d_in[0];
  const int*   ei = (const int*)d_in[1];
  const int*   et = (const int*)d_in[2];
  const float* W  = (const float*)d_in[4];
  const float* W0 = (const float*)d_in[5];
  float* out = (float*)d_out;

  const int N = in_sizes[0] / NDIM;   // 50000
  const int E = in_sizes[2];          // 800000

  char* ws = (char*)d_ws;
  size_t off = 0;
  auto alloc = [&](size_t bytes)->size_t{
    size_t p = off; off = (off + bytes + 255) & ~(size_t)255; return p;
  };
  size_t o_flag = alloc(4);
  size_t o_st   = alloc((size_t)E * 4);
  size_t o_d    = alloc((size_t)E * 4);
  size_t o_deg  = alloc((size_t)N * 4);
  size_t o_rs   = alloc((size_t)(N + 1) * 4);
  size_t o_cur  = alloc((size_t)N * 4);
  size_t o_bs   = alloc(256 * 4);
  size_t o_bo   = alloc(256 * 4);
  size_t o_es   = alloc((size_t)E * 4);
  size_t o_h    = alloc((size_t)NREL * N * NDIM * 2);   // bf16
  size_t o_inv  = alloc((size_t)N * 4);
  size_t o_wb   = alloc((size_t)9 * NDIM * NDIM * 2);   // bf16 W^T
  (void)ws_size;

  int*  flag   = (int*)(ws + o_flag);
  int*  st     = (int*)(ws + o_st);
  int*  darr   = (int*)(ws + o_d);
  int*  deg    = (int*)(ws + o_deg);
  int*  rs     = (int*)(ws + o_rs);
  int*  cursor = (int*)(ws + o_cur);
  int*  bsum   = (int*)(ws + o_bs);
  int*  boff   = (int*)(ws + o_bo);
  int*  esort  = (int*)(ws + o_es);
  __hip_bfloat162* h2 = (__hip_bfloat162*)(ws + o_h);
  __hip_bfloat16*  h1 = (__hip_bfloat16*)(ws + o_h);
  float* invdeg = (float*)(ws + o_inv);
  short* Wbs    = (short*)(ws + o_wb);

  const int nblk = (N + 255) / 256;
  const int eblk = (E + 255) / 256;

  k_wcast<<<(9 * NDIM * NDIM + 255) / 256, 256, 0, stream>>>(W, W0, Wbs);
  k_zero<<<nblk, 256, 0, stream>>>(deg, N);
  k_detect<<<1, 64, 0, stream>>>(ei, flag);
  k_norm<<<eblk, 256, 0, stream>>>(ei, et, flag, st, darr, deg, E);
  k_scanA<<<nblk, 256, 0, stream>>>(deg, rs, bsum, N);
  k_scanB<<<1, 256, 0, stream>>>(bsum, boff, nblk);
  k_scanC<<<nblk, 256, 0, stream>>>(rs, cursor, boff, N, E);
  k_scatter<<<eblk, 256, 0, stream>>>(st, darr, cursor, esort, E);
  k_agg<<<(N + 3) / 4, 256, 0, stream>>>(x, rs, esort, h2, invdeg, N);
  k_mfma<<<(N + 63) / 64, 256, 0, stream>>>(h1, x, Wbs, invdeg, out, N);
}

// Round 3
// 205.948 us; speedup vs baseline: 4.2464x; 1.4447x over previous
//
#include <hip/hip_runtime.h>
#include <hip/hip_bf16.h>
#include <cstdint>
#include <cstddef>

// RGCN layer: out = (x@W0 + sum_r h_r@W[r]) / max(deg,1)
// h_cat[n][r*128+k] = sum over edges (src->dst=n, type r) of x[src][k]; slot r=8 holds bf16(x[n]).
// out = (h_cat @ Wb^T) * invdeg  -- one GEMM, M=N nodes, K=1152, N=128.
// GEMM uses m97 structure: global_load_lds(16B) -> double-buffered swizzled LDS -> MFMA.

#define NDIM 128
#define NREL 8
#define KCAT 1152   // 9*128

typedef __attribute__((ext_vector_type(8))) short bf16x8;
typedef __attribute__((ext_vector_type(4))) float f32x4;

__device__ __forceinline__ short f2bf(float f){
  __hip_bfloat16 h = __float2bfloat16(f);
  return *reinterpret_cast<short*>(&h);
}

__device__ __forceinline__ void gload_lds16(const void* g, void* l){
  __builtin_amdgcn_global_load_lds(
      (const __attribute__((address_space(1))) unsigned int*)g,
      (__attribute__((address_space(3))) unsigned int*)l, 16, 0, 0);
}

// ---------- K0: zero int buffer ----------
__global__ void k_zero(int* p, int n){
  int i = blockIdx.x * 256 + threadIdx.x;
  if (i < n) p[i] = 0;
}

// ---------- K1: detect int64 vs int32 edge arrays ----------
__global__ void k_detect(const int* ei, int* flag){
  int v = ei[2 * threadIdx.x + 1];
  unsigned long long b = __ballot(v == 0);
  if (threadIdx.x == 0) flag[0] = (b == ~0ull) ? 1 : 0;
}

// ---------- K2: normalize edges + degree histogram ----------
__global__ void k_norm(const int* ei, const int* et, const int* __restrict__ flag,
                       int* st, int* darr, int* deg, int E){
  int e = blockIdx.x * 256 + threadIdx.x;
  if (e >= E) return;
  int is64 = flag[0];
  int s, d, t;
  if (is64){ s = ei[2*e]; d = ei[2*(E + e)]; t = et[2*e]; }
  else     { s = ei[e];   d = ei[E + e];     t = et[e];   }
  st[e]   = s | (t << 20);
  darr[e] = d;
  atomicAdd(&deg[d], 1);
}

// ---------- K3/K4/K5: exclusive scan ----------
__global__ void k_scanA(const int* deg, int* rs, int* bsum, int N){
  __shared__ int sm[256];
  int t = threadIdx.x, i = blockIdx.x * 256 + t;
  int v = (i < N) ? deg[i] : 0;
  sm[t] = v; __syncthreads();
  #pragma unroll
  for (int off = 1; off < 256; off <<= 1){
    int xv = 0; if (t >= off) xv = sm[t - off];
    __syncthreads(); sm[t] += xv; __syncthreads();
  }
  if (i < N) rs[i] = sm[t] - v;
  if (t == 255) bsum[blockIdx.x] = sm[255];
}

__global__ void k_scanB(const int* bsum, int* boff, int nblk){
  __shared__ int sm[256];
  int t = threadIdx.x;
  int v = (t < nblk) ? bsum[t] : 0;
  sm[t] = v; __syncthreads();
  #pragma unroll
  for (int off = 1; off < 256; off <<= 1){
    int xv = 0; if (t >= off) xv = sm[t - off];
    __syncthreads(); sm[t] += xv; __syncthreads();
  }
  boff[t] = sm[t] - v;
}

__global__ void k_scanC(int* rs, int* cursor, const int* boff, int N, int E){
  int i = blockIdx.x * 256 + threadIdx.x;
  if (i < N){
    int v = rs[i] + boff[blockIdx.x];
    rs[i] = v; cursor[i] = v;
  }
  if (i == 0) rs[N] = E;
}

// ---------- K6: scatter edges into CSR buckets ----------
__global__ void k_scatter(const int* st, const int* darr, int* cursor, int* esort, int E){
  int e = blockIdx.x * 256 + threadIdx.x;
  if (e >= E) return;
  int pos = atomicAdd(&cursor[darr[e]], 1);
  esort[pos] = st[e];
}

// ---------- K7: aggregation -> h_cat[n][1152] bf16 (+ x slot), invdeg ----------
// 1 wave per node; lane owns cols {2l,2l+1}; 4-wide edge unroll for MLP-level ILP.
__global__ __launch_bounds__(256) void k_agg(const float* __restrict__ x,
                                             const int* __restrict__ rs,
                                             const int* __restrict__ esort,
                                             __hip_bfloat162* __restrict__ hcat,
                                             float* __restrict__ invdeg, int N){
  int wave = threadIdx.x >> 6;
  int lane = threadIdx.x & 63;
  int n = blockIdx.x * 4 + wave;
  if (n >= N) return;
  int beg = rs[n], end = rs[n + 1];
  float2 acc[NREL];
  #pragma unroll
  for (int r = 0; r < NREL; ++r){ acc[r].x = 0.f; acc[r].y = 0.f; }
  const float2* x2 = (const float2*)x;

  int i = beg;
  for (; i + 3 < end; i += 4){
    int p0 = esort[i], p1 = esort[i+1], p2 = esort[i+2], p3 = esort[i+3];
    float2 v0 = x2[(size_t)(p0 & 0xFFFFF) * 64 + lane];
    float2 v1 = x2[(size_t)(p1 & 0xFFFFF) * 64 + lane];
    float2 v2 = x2[(size_t)(p2 & 0xFFFFF) * 64 + lane];
    float2 v3 = x2[(size_t)(p3 & 0xFFFFF) * 64 + lane];
    switch (p0 >> 20){
      case 0: acc[0].x+=v0.x; acc[0].y+=v0.y; break; case 1: acc[1].x+=v0.x; acc[1].y+=v0.y; break;
      case 2: acc[2].x+=v0.x; acc[2].y+=v0.y; break; case 3: acc[3].x+=v0.x; acc[3].y+=v0.y; break;
      case 4: acc[4].x+=v0.x; acc[4].y+=v0.y; break; case 5: acc[5].x+=v0.x; acc[5].y+=v0.y; break;
      case 6: acc[6].x+=v0.x; acc[6].y+=v0.y; break; case 7: acc[7].x+=v0.x; acc[7].y+=v0.y; break;
    }
    switch (p1 >> 20){
      case 0: acc[0].x+=v1.x; acc[0].y+=v1.y; break; case 1: acc[1].x+=v1.x; acc[1].y+=v1.y; break;
      case 2: acc[2].x+=v1.x; acc[2].y+=v1.y; break; case 3: acc[3].x+=v1.x; acc[3].y+=v1.y; break;
      case 4: acc[4].x+=v1.x; acc[4].y+=v1.y; break; case 5: acc[5].x+=v1.x; acc[5].y+=v1.y; break;
      case 6: acc[6].x+=v1.x; acc[6].y+=v1.y; break; case 7: acc[7].x+=v1.x; acc[7].y+=v1.y; break;
    }
    switch (p2 >> 20){
      case 0: acc[0].x+=v2.x; acc[0].y+=v2.y; break; case 1: acc[1].x+=v2.x; acc[1].y+=v2.y; break;
      case 2: acc[2].x+=v2.x; acc[2].y+=v2.y; break; case 3: acc[3].x+=v2.x; acc[3].y+=v2.y; break;
      case 4: acc[4].x+=v2.x; acc[4].y+=v2.y; break; case 5: acc[5].x+=v2.x; acc[5].y+=v2.y; break;
      case 6: acc[6].x+=v2.x; acc[6].y+=v2.y; break; case 7: acc[7].x+=v2.x; acc[7].y+=v2.y; break;
    }
    switch (p3 >> 20){
      case 0: acc[0].x+=v3.x; acc[0].y+=v3.y; break; case 1: acc[1].x+=v3.x; acc[1].y+=v3.y; break;
      case 2: acc[2].x+=v3.x; acc[2].y+=v3.y; break; case 3: acc[3].x+=v3.x; acc[3].y+=v3.y; break;
      case 4: acc[4].x+=v3.x; acc[4].y+=v3.y; break; case 5: acc[5].x+=v3.x; acc[5].y+=v3.y; break;
      case 6: acc[6].x+=v3.x; acc[6].y+=v3.y; break; case 7: acc[7].x+=v3.x; acc[7].y+=v3.y; break;
    }
  }
  for (; i < end; ++i){
    int p = esort[i];
    float2 v = x2[(size_t)(p & 0xFFFFF) * 64 + lane];
    switch (p >> 20){
      case 0: acc[0].x+=v.x; acc[0].y+=v.y; break; case 1: acc[1].x+=v.x; acc[1].y+=v.y; break;
      case 2: acc[2].x+=v.x; acc[2].y+=v.y; break; case 3: acc[3].x+=v.x; acc[3].y+=v.y; break;
      case 4: acc[4].x+=v.x; acc[4].y+=v.y; break; case 5: acc[5].x+=v.x; acc[5].y+=v.y; break;
      case 6: acc[6].x+=v.x; acc[6].y+=v.y; break; case 7: acc[7].x+=v.x; acc[7].y+=v.y; break;
    }
  }

  size_t base2 = (size_t)n * (KCAT / 2);   // bf162 units
  #pragma unroll
  for (int r = 0; r < NREL; ++r)
    hcat[base2 + r * 64 + lane] = __float22bfloat162_rn(acc[r]);
  float2 xv = x2[(size_t)n * 64 + lane];    // self slot (r=8)
  hcat[base2 + 512 + lane] = __float22bfloat162_rn(xv);
  if (lane == 0){
    int d = end - beg;
    invdeg[n] = 1.0f / (float)(d > 0 ? d : 1);
  }
}

// ---------- K8a: W,W0 -> Wb[j][KCAT] bf16: Wb[j][r*128+kd] = W[r][kd][j] ----------
__global__ void k_wcast(const float* __restrict__ W, const float* __restrict__ W0,
                        short* __restrict__ Wb){
  int i = blockIdx.x * 256 + threadIdx.x;      // 128*1152 = 147456
  if (i >= NDIM * KCAT) return;
  int j  = i / KCAT;
  int t  = i - j * KCAT;
  int r  = t >> 7;
  int kd = t & 127;
  float v = (r < NREL) ? W[(((size_t)r * NDIM + kd) << 7) + j] : W0[((size_t)kd << 7) + j];
  Wb[i] = f2bf(v);
}

// ---------- K8b: GEMM out[n][j] = (A[n][:] . Wb[j][:]) * invdeg[n] ----------
// BM=64, BN=128, BK=64; 4 waves, wave tile 32x64 (2x4 frags of 16x16x32 bf16).
// m97 structure: gl_lds(16B) double-buffer, XOR-swizzled LDS (linear dest +
// pre-swizzled src + swizzled read), one barrier per K-step, 18 K-steps.
__global__ __launch_bounds__(256) void k_gemm2(
    const short* __restrict__ acat,   // [Npad][1152] bf16
    const short* __restrict__ wb,     // [128][1152]  bf16
    const float* __restrict__ invdeg,
    float* __restrict__ out, int N)
{
  __shared__ char smem[49152];        // As0 8K | As1 8K | Bs0 16K | Bs1 16K
  char* As0 = smem;
  char* As1 = smem + 8192;
  char* Bs0 = smem + 16384;
  char* Bs1 = smem + 32768;

  const int tid  = threadIdx.x;
  const int lane = tid & 63;
  const int wid  = tid >> 6;
  const int wr   = wid >> 1;
  const int wc   = wid & 1;
  const int n0   = blockIdx.x * 64;
  const int lr   = lane & 15;
  const int lq   = lane >> 4;

  f32x4 acc[2][4];
  #pragma unroll
  for (int m = 0; m < 2; ++m)
    #pragma unroll
    for (int p = 0; p < 4; ++p)
      acc[m][p] = (f32x4){0.f, 0.f, 0.f, 0.f};

  const int srow = tid >> 3;   // staging row-within-32 block
  const int scs  = tid & 7;    // staging 16B-chunk slot

  auto STAGE = [&](char* Ab, char* Bb, int ks){
    const short* ab = acat + (size_t)n0 * KCAT + ks * 64;
    #pragma unroll
    for (int q = 0; q < 2; ++q){
      int row = q * 32 + srow;
      const short* src = ab + (size_t)row * KCAT + ((scs ^ (row & 7)) << 3);
      gload_lds16(src, Ab + q * 4096 + (wid << 10));
    }
    const short* bb = wb + ks * 64;
    #pragma unroll
    for (int q = 0; q < 4; ++q){
      int j = q * 32 + srow;
      const short* src = bb + (size_t)j * KCAT + ((scs ^ (j & 7)) << 3);
      gload_lds16(src, Bb + q * 4096 + (wid << 10));
    }
  };

  auto COMPUTE = [&](const char* Ab, const char* Bb){
    bf16x8 a[2][2], b[2][4];
    #pragma unroll
    for (int kk = 0; kk < 2; ++kk){
      #pragma unroll
      for (int m = 0; m < 2; ++m){
        int row = wr * 32 + m * 16 + lr;
        int c   = kk * 4 + lq;
        a[kk][m] = *(const bf16x8*)(Ab + row * 128 + ((c ^ (row & 7)) << 4));
      }
      #pragma unroll
      for (int p = 0; p < 4; ++p){
        int j = wc * 64 + p * 16 + lr;
        int c = kk * 4 + lq;
        b[kk][p] = *(const bf16x8*)(Bb + j * 128 + ((c ^ (j & 7)) << 4));
      }
    }
    #pragma unroll
    for (int kk = 0; kk < 2; ++kk)
      #pragma unroll
      for (int m = 0; m < 2; ++m)
        #pragma unroll
        for (int p = 0; p < 4; ++p)
          acc[m][p] = __builtin_amdgcn_mfma_f32_16x16x32_bf16(a[kk][m], b[kk][p], acc[m][p], 0, 0, 0);
  };

  STAGE(As0, Bs0, 0);
  __syncthreads();
  for (int ks = 0; ks < 18; ks += 2){
    STAGE(As1, Bs1, ks + 1);
    COMPUTE(As0, Bs0);
    __syncthreads();
    if (ks + 2 < 18) STAGE(As0, Bs0, ks + 2);
    COMPUTE(As1, Bs1);
    __syncthreads();
  }

  // Epilogue: C/D layout col=lane&15, row=(lane>>4)*4+v
  #pragma unroll
  for (int m = 0; m < 2; ++m){
    int rbase = n0 + wr * 32 + m * 16 + lq * 4;
    #pragma unroll
    for (int v = 0; v < 4; ++v){
      int ro = rbase + v;
      if (ro < N){
        float inv = invdeg[ro];
        #pragma unroll
        for (int p = 0; p < 4; ++p)
          out[(((size_t)ro) << 7) + wc * 64 + p * 16 + lr] = acc[m][p][v] * inv;
      }
    }
  }
}

extern "C" void kernel_launch(void* const* d_in, const int* in_sizes, int n_in,
                              void* d_out, int out_size, void* d_ws, size_t ws_size,
                              hipStream_t stream){
  const float* x  = (const float*)d_in[0];
  const int*   ei = (const int*)d_in[1];
  const int*   et = (const int*)d_in[2];
  const float* W  = (const float*)d_in[4];
  const float* W0 = (const float*)d_in[5];
  float* out = (float*)d_out;

  const int N = in_sizes[0] / NDIM;   // 50000
  const int E = in_sizes[2];          // 800000
  const int Npad = N + 64;            // GEMM tail tile reads stay in-bounds

  char* ws = (char*)d_ws;
  size_t off = 0;
  auto alloc = [&](size_t bytes)->size_t{
    size_t p = off; off = (off + bytes + 255) & ~(size_t)255; return p;
  };
  size_t o_flag = alloc(4);
  size_t o_st   = alloc((size_t)E * 4);
  size_t o_d    = alloc((size_t)E * 4);
  size_t o_deg  = alloc((size_t)N * 4);
  size_t o_rs   = alloc((size_t)(N + 1) * 4);
  size_t o_cur  = alloc((size_t)N * 4);
  size_t o_bs   = alloc(256 * 4);
  size_t o_bo   = alloc(256 * 4);
  size_t o_es   = alloc((size_t)E * 4);
  size_t o_h    = alloc((size_t)Npad * KCAT * 2);       // bf16 A_cat
  size_t o_inv  = alloc((size_t)N * 4);
  size_t o_wb   = alloc((size_t)NDIM * KCAT * 2);       // bf16 Wb
  (void)ws_size;

  int*  flag   = (int*)(ws + o_flag);
  int*  st     = (int*)(ws + o_st);
  int*  darr   = (int*)(ws + o_d);
  int*  deg    = (int*)(ws + o_deg);
  int*  rs     = (int*)(ws + o_rs);
  int*  cursor = (int*)(ws + o_cur);
  int*  bsum   = (int*)(ws + o_bs);
  int*  boff   = (int*)(ws + o_bo);
  int*  esort  = (int*)(ws + o_es);
  __hip_bfloat162* h2 = (__hip_bfloat162*)(ws + o_h);
  short* acat  = (short*)(ws + o_h);
  float* invdeg = (float*)(ws + o_inv);
  short* Wbs   = (short*)(ws + o_wb);

  const int nblk = (N + 255) / 256;
  const int eblk = (E + 255) / 256;

  k_wcast<<<(NDIM * KCAT + 255) / 256, 256, 0, stream>>>(W, W0, Wbs);
  k_zero<<<nblk, 256, 0, stream>>>(deg, N);
  k_detect<<<1, 64, 0, stream>>>(ei, flag);
  k_norm<<<eblk, 256, 0, stream>>>(ei, et, flag, st, darr, deg, E);
  k_scanA<<<nblk, 256, 0, stream>>>(deg, rs, bsum, N);
  k_scanB<<<1, 256, 0, stream>>>(bsum, boff, nblk);
  k_scanC<<<nblk, 256, 0, stream>>>(rs, cursor, boff, N, E);
  k_scatter<<<eblk, 256, 0, stream>>>(st, darr, cursor, esort, E);
  k_agg<<<(N + 3) / 4, 256, 0, stream>>>(x, rs, esort, h2, invdeg, N);
  k_gemm2<<<(N + 63) / 64, 256, 0, stream>>>(acat, Wbs, invdeg, out, N);
}